// Round 1
// baseline (9546.346 us; speedup 1.0000x reference)
//
#include <hip/hip_runtime.h>
#include <hip/hip_bf16.h>
#include <math.h>

#define NN   10000
#define EE   160000
#define CC   128
#define RBFD 20
#define HIDD 32
#define WND  384
#define MROW 1152   // 9*128 accumulator row: [m=0..8][c=0..127]

// Fallback accumulator if d_ws is too small (zero-init .bss, 46 MB).
__device__ __align__(16) float g_accu[(size_t)NN * MROW];

__device__ __forceinline__ float silu_f(float x) { return x / (1.f + __expf(-x)); }

__global__ __launch_bounds__(256) void zero_kernel(float* accu, int n4)
{
    float4* p = reinterpret_cast<float4*>(accu ? accu : g_accu);
    float4 z = make_float4(0.f, 0.f, 0.f, 0.f);
    for (int i = blockIdx.x * blockDim.x + threadIdx.x; i < n4; i += gridDim.x * blockDim.x)
        p[i] = z;
}

__global__ __launch_bounds__(256) void edge_kernel(
    const float* __restrict__ node_feat,
    const float* __restrict__ edge_attr,
    const float* __restrict__ edge_rsh,
    const int*   __restrict__ edge_index,
    const float* __restrict__ Ws1, const float* __restrict__ bs1,
    const float* __restrict__ Ws2, const float* __restrict__ bs2,
    const float* __restrict__ Wr1, const float* __restrict__ br1,
    const float* __restrict__ Wr2, const float* __restrict__ br2,
    float* accu)
{
    float* A = accu ? accu : g_accu;
    int e = blockIdx.x * 256 + threadIdx.x;
    if (e >= EE) return;

    int s = edge_index[e];        // src (gather + segment key)
    int t = edge_index[EE + e];   // dst (xj)
    const float* xi = node_feat + (size_t)s * CC;
    const float* xj = node_feat + (size_t)t * CC;

    // ---- MLP-s hidden: hs[j] = silu( sum_k [xi|xj][k] * Ws1[k][j] + bs1[j] )
    float hs[HIDD];
    #pragma unroll
    for (int j = 0; j < HIDD; ++j) hs[j] = bs1[j];
    #pragma unroll 1
    for (int k4 = 0; k4 < CC / 4; ++k4) {
        float4 a = reinterpret_cast<const float4*>(xi)[k4];
        const float* w = Ws1 + (4 * k4) * HIDD;
        #pragma unroll
        for (int j = 0; j < HIDD; ++j) {
            hs[j] = fmaf(a.x, w[j],            hs[j]);
            hs[j] = fmaf(a.y, w[HIDD + j],     hs[j]);
            hs[j] = fmaf(a.z, w[2 * HIDD + j], hs[j]);
            hs[j] = fmaf(a.w, w[3 * HIDD + j], hs[j]);
        }
    }
    #pragma unroll 1
    for (int k4 = 0; k4 < CC / 4; ++k4) {
        float4 a = reinterpret_cast<const float4*>(xj)[k4];
        const float* w = Ws1 + (CC + 4 * k4) * HIDD;
        #pragma unroll
        for (int j = 0; j < HIDD; ++j) {
            hs[j] = fmaf(a.x, w[j],            hs[j]);
            hs[j] = fmaf(a.y, w[HIDD + j],     hs[j]);
            hs[j] = fmaf(a.z, w[2 * HIDD + j], hs[j]);
            hs[j] = fmaf(a.w, w[3 * HIDD + j], hs[j]);
        }
    }
    #pragma unroll
    for (int j = 0; j < HIDD; ++j) hs[j] = silu_f(hs[j]);

    // ---- MLP-r hidden
    float hr[HIDD];
    #pragma unroll
    for (int j = 0; j < HIDD; ++j) hr[j] = br1[j];
    #pragma unroll 1
    for (int k4 = 0; k4 < RBFD / 4; ++k4) {
        float4 a = reinterpret_cast<const float4*>(edge_attr + (size_t)e * RBFD)[k4];
        const float* w = Wr1 + (4 * k4) * HIDD;
        #pragma unroll
        for (int j = 0; j < HIDD; ++j) {
            hr[j] = fmaf(a.x, w[j],            hr[j]);
            hr[j] = fmaf(a.y, w[HIDD + j],     hr[j]);
            hr[j] = fmaf(a.z, w[2 * HIDD + j], hr[j]);
            hr[j] = fmaf(a.w, w[3 * HIDD + j], hr[j]);
        }
    }
    #pragma unroll
    for (int j = 0; j < HIDD; ++j) hr[j] = silu_f(hr[j]);

    // ---- spherical harmonics coefficients
    float y[9];
    #pragma unroll
    for (int i = 0; i < 9; ++i) y[i] = edge_rsh[(size_t)e * 9 + i];

    // ---- second GEMM + tensor-product message + atomic scatter, per channel
    size_t base = (size_t)s * MROW;
    #pragma unroll 1
    for (int c = 0; c < CC; ++c) {
        float as0 = bs2[c], as1 = bs2[CC + c], as2 = bs2[2 * CC + c];
        float ar0 = br2[c], ar1 = br2[CC + c], ar2 = br2[2 * CC + c];
        #pragma unroll
        for (int j = 0; j < HIDD; ++j) {
            float hsv = hs[j], hrv = hr[j];
            const float* wp = Ws2 + j * WND;
            const float* rp = Wr2 + j * WND;
            as0 = fmaf(hsv, wp[c],          as0);
            as1 = fmaf(hsv, wp[CC + c],     as1);
            as2 = fmaf(hsv, wp[2 * CC + c], as2);
            ar0 = fmaf(hrv, rp[c],          ar0);
            ar1 = fmaf(hrv, rp[CC + c],     ar1);
            ar2 = fmaf(hrv, rp[2 * CC + c], ar2);
        }
        float xjc = xj[c];
        float w0 = as0 * ar0 * xjc;
        float w1 = as1 * ar1 * xjc;
        float w2 = as2 * ar2 * xjc;
        // accumulator layout: A[n][m][c], m=0 -> l0, m=1..3 -> l1, m=4..8 -> l2
        unsafeAtomicAdd(&A[base + c],          w0 * y[0]);
        unsafeAtomicAdd(&A[base + CC + c],     w1 * y[1]);
        unsafeAtomicAdd(&A[base + 2 * CC + c], w1 * y[2]);
        unsafeAtomicAdd(&A[base + 3 * CC + c], w1 * y[3]);
        #pragma unroll
        for (int m = 0; m < 5; ++m)
            unsafeAtomicAdd(&A[base + (size_t)(4 + m) * CC + c], w2 * y[4 + m]);
    }
}

// Node-wise linear: out[n, d]        = inv * sum_c A[n][0][c]   W0[c][d] + b0[d]
//                   out[n,128+d*3+m] = inv * sum_c A[n][1+m][c] W1[c][d]
//                   out[n,512+d*5+m] = inv * sum_c A[n][4+m][c] W2[c][d]
__global__ __launch_bounds__(256) void lin2_kernel(
    const float* accu,
    const float* __restrict__ W0, const float* __restrict__ b0,
    const float* __restrict__ W1, const float* __restrict__ W2,
    float* __restrict__ out)
{
    const float* A = accu ? accu : g_accu;
    __shared__ float sA[2 * MROW];
    int n0 = blockIdx.x * 2;
    const float4* g = reinterpret_cast<const float4*>(A + (size_t)n0 * MROW);
    for (int i = threadIdx.x; i < 2 * MROW / 4; i += 256)
        reinterpret_cast<float4*>(sA)[i] = g[i];
    __syncthreads();

    int d  = threadIdx.x & (CC - 1);
    int nl = threadIdx.x >> 7;           // 0 or 1
    const float* a = sA + nl * MROW;

    float acc[9];
    #pragma unroll
    for (int m = 0; m < 9; ++m) acc[m] = 0.f;

    #pragma unroll 2
    for (int c = 0; c < CC; ++c) {
        float w0 = W0[c * CC + d];
        float w1 = W1[c * CC + d];
        float w2 = W2[c * CC + d];
        acc[0] = fmaf(a[c],           w0, acc[0]);
        acc[1] = fmaf(a[CC + c],      w1, acc[1]);
        acc[2] = fmaf(a[2 * CC + c],  w1, acc[2]);
        acc[3] = fmaf(a[3 * CC + c],  w1, acc[3]);
        acc[4] = fmaf(a[4 * CC + c],  w2, acc[4]);
        acc[5] = fmaf(a[5 * CC + c],  w2, acc[5]);
        acc[6] = fmaf(a[6 * CC + c],  w2, acc[6]);
        acc[7] = fmaf(a[7 * CC + c],  w2, acc[7]);
        acc[8] = fmaf(a[8 * CC + c],  w2, acc[8]);
    }

    const float inv = 0.08838834764831845f;  // 1/sqrt(128)
    size_t ob = (size_t)(n0 + nl) * MROW;
    out[ob + d] = acc[0] * inv + b0[d];
    #pragma unroll
    for (int m = 0; m < 3; ++m) out[ob + CC + d * 3 + m]     = acc[1 + m] * inv;
    #pragma unroll
    for (int m = 0; m < 5; ++m) out[ob + 4 * CC + d * 5 + m] = acc[4 + m] * inv;
}

extern "C" void kernel_launch(void* const* d_in, const int* in_sizes, int n_in,
                              void* d_out, int out_size, void* d_ws, size_t ws_size,
                              hipStream_t stream)
{
    const float* node_feat  = (const float*)d_in[0];
    const float* edge_attr  = (const float*)d_in[1];
    const float* edge_rsh   = (const float*)d_in[2];
    const int*   edge_index = (const int*)  d_in[3];
    const float* Ws1 = (const float*)d_in[4];
    const float* bs1 = (const float*)d_in[5];
    const float* Ws2 = (const float*)d_in[6];
    const float* bs2 = (const float*)d_in[7];
    const float* Wr1 = (const float*)d_in[8];
    const float* br1 = (const float*)d_in[9];
    const float* Wr2 = (const float*)d_in[10];
    const float* br2 = (const float*)d_in[11];
    const float* W0  = (const float*)d_in[12];
    const float* b0  = (const float*)d_in[13];
    const float* W1  = (const float*)d_in[14];
    const float* W2  = (const float*)d_in[15];
    float* out = (float*)d_out;

    size_t need = (size_t)NN * MROW * sizeof(float);
    float* accu = (ws_size >= need) ? (float*)d_ws : nullptr;  // nullptr -> g_accu

    zero_kernel<<<2048, 256, 0, stream>>>(accu, NN * MROW / 4);
    edge_kernel<<<(EE + 255) / 256, 256, 0, stream>>>(
        node_feat, edge_attr, edge_rsh, edge_index,
        Ws1, bs1, Ws2, bs2, Wr1, br1, Wr2, br2, accu);
    lin2_kernel<<<NN / 2, 256, 0, stream>>>(accu, W0, b0, W1, W2, out);
}

// Round 2
// 907.757 us; speedup vs baseline: 10.5164x; 10.5164x over previous
//
#include <hip/hip_runtime.h>
#include <hip/hip_bf16.h>
#include <math.h>

#define NN   10000
#define EE   160000
#define CC   128
#define RBFD 20
#define HIDD 32
#define WND  384
#define MROW 1152   // 9*128 accumulator row: [m=0..8][c=0..127]

// Static device buffers (persist across calls; every element rewritten each call).
__device__ __align__(16) float g_u[(size_t)EE * WND];     // 245.8 MB: sorted (w*xj) per edge [row][m(3)][c(128)]
__device__ __align__(16) float g_y[(size_t)EE * 9];       // 5.8 MB: sorted SH coeffs
__device__ __align__(16) float g_accu[(size_t)NN * MROW]; // 46 MB: per-node accumulator [n][m(9)][c]
__device__ int g_deg[NN];
__device__ int g_offs[NN + 1];
__device__ int g_rel[EE];

__device__ __forceinline__ float silu_f(float x) { return x / (1.f + __expf(-x)); }

__global__ __launch_bounds__(256) void zero_deg_kernel()
{
    int i = blockIdx.x * 256 + threadIdx.x;
    if (i < NN) g_deg[i] = 0;
}

__global__ __launch_bounds__(256) void hist_kernel(const int* __restrict__ edge_index)
{
    int e = blockIdx.x * 256 + threadIdx.x;
    if (e < EE) g_rel[e] = atomicAdd(&g_deg[edge_index[e]], 1);
}

// Single-block exclusive scan over g_deg -> g_offs
__global__ __launch_bounds__(1024) void scan_kernel()
{
    __shared__ int s[1024];
    __shared__ int carry;
    if (threadIdx.x == 0) { carry = 0; g_offs[0] = 0; }
    __syncthreads();
    for (int base = 0; base < NN; base += 1024) {
        int i = base + threadIdx.x;
        int v = (i < NN) ? g_deg[i] : 0;
        s[threadIdx.x] = v;
        __syncthreads();
        for (int off = 1; off < 1024; off <<= 1) {
            int t = (threadIdx.x >= off) ? s[threadIdx.x - off] : 0;
            __syncthreads();
            s[threadIdx.x] += t;
            __syncthreads();
        }
        if (i < NN) g_offs[i + 1] = carry + s[threadIdx.x];
        __syncthreads();
        if (threadIdx.x == 0) carry += s[1023];
        __syncthreads();
    }
}

// Per-edge MLPs; writes u=(w_s*w_r*xj) and y into CSR-sorted rows. No atomics.
__global__ __launch_bounds__(256) void mlp_kernel(
    const float* __restrict__ node_feat,
    const float* __restrict__ edge_attr,
    const float* __restrict__ edge_rsh,
    const int*   __restrict__ edge_index,
    const float* __restrict__ Ws1, const float* __restrict__ bs1,
    const float* __restrict__ Ws2, const float* __restrict__ bs2,
    const float* __restrict__ Wr1, const float* __restrict__ br1,
    const float* __restrict__ Wr2, const float* __restrict__ br2)
{
    int e = blockIdx.x * 256 + threadIdx.x;
    if (e >= EE) return;

    int s = edge_index[e];        // src (segment key)
    int t = edge_index[EE + e];   // dst (xj)
    const float* xi = node_feat + (size_t)s * CC;
    const float* xj = node_feat + (size_t)t * CC;

    // ---- MLP-s hidden
    float hs[HIDD];
    #pragma unroll
    for (int j = 0; j < HIDD; ++j) hs[j] = bs1[j];
    #pragma unroll 1
    for (int k4 = 0; k4 < CC / 4; ++k4) {
        float4 a = reinterpret_cast<const float4*>(xi)[k4];
        const float* w = Ws1 + (4 * k4) * HIDD;
        #pragma unroll
        for (int j = 0; j < HIDD; ++j) {
            hs[j] = fmaf(a.x, w[j],            hs[j]);
            hs[j] = fmaf(a.y, w[HIDD + j],     hs[j]);
            hs[j] = fmaf(a.z, w[2 * HIDD + j], hs[j]);
            hs[j] = fmaf(a.w, w[3 * HIDD + j], hs[j]);
        }
    }
    #pragma unroll 1
    for (int k4 = 0; k4 < CC / 4; ++k4) {
        float4 a = reinterpret_cast<const float4*>(xj)[k4];
        const float* w = Ws1 + (CC + 4 * k4) * HIDD;
        #pragma unroll
        for (int j = 0; j < HIDD; ++j) {
            hs[j] = fmaf(a.x, w[j],            hs[j]);
            hs[j] = fmaf(a.y, w[HIDD + j],     hs[j]);
            hs[j] = fmaf(a.z, w[2 * HIDD + j], hs[j]);
            hs[j] = fmaf(a.w, w[3 * HIDD + j], hs[j]);
        }
    }
    #pragma unroll
    for (int j = 0; j < HIDD; ++j) hs[j] = silu_f(hs[j]);

    // ---- MLP-r hidden
    float hr[HIDD];
    #pragma unroll
    for (int j = 0; j < HIDD; ++j) hr[j] = br1[j];
    #pragma unroll 1
    for (int k4 = 0; k4 < RBFD / 4; ++k4) {
        float4 a = reinterpret_cast<const float4*>(edge_attr + (size_t)e * RBFD)[k4];
        const float* w = Wr1 + (4 * k4) * HIDD;
        #pragma unroll
        for (int j = 0; j < HIDD; ++j) {
            hr[j] = fmaf(a.x, w[j],            hr[j]);
            hr[j] = fmaf(a.y, w[HIDD + j],     hr[j]);
            hr[j] = fmaf(a.z, w[2 * HIDD + j], hr[j]);
            hr[j] = fmaf(a.w, w[3 * HIDD + j], hr[j]);
        }
    }
    #pragma unroll
    for (int j = 0; j < HIDD; ++j) hr[j] = silu_f(hr[j]);

    // ---- CSR-sorted destination row
    size_t row = (size_t)g_offs[s] + g_rel[e];
    float4* uw = reinterpret_cast<float4*>(g_u + row * WND);

    // ---- MLP2 (both branches) + tensor-product weight, 4 channels at a time
    #pragma unroll 1
    for (int c4 = 0; c4 < CC / 4; ++c4) {
        int c = c4 * 4;
        float a0[4], a1[4], a2[4], r0[4], r1[4], r2[4];
        #pragma unroll
        for (int q = 0; q < 4; ++q) {
            a0[q] = bs2[c + q]; a1[q] = bs2[CC + c + q]; a2[q] = bs2[2 * CC + c + q];
            r0[q] = br2[c + q]; r1[q] = br2[CC + c + q]; r2[q] = br2[2 * CC + c + q];
        }
        #pragma unroll
        for (int j = 0; j < HIDD; ++j) {
            float hsv = hs[j], hrv = hr[j];
            const float* wp = Ws2 + j * WND + c;
            const float* rp = Wr2 + j * WND + c;
            #pragma unroll
            for (int q = 0; q < 4; ++q) {
                a0[q] = fmaf(hsv, wp[q],          a0[q]);
                a1[q] = fmaf(hsv, wp[CC + q],     a1[q]);
                a2[q] = fmaf(hsv, wp[2 * CC + q], a2[q]);
                r0[q] = fmaf(hrv, rp[q],          r0[q]);
                r1[q] = fmaf(hrv, rp[CC + q],     r1[q]);
                r2[q] = fmaf(hrv, rp[2 * CC + q], r2[q]);
            }
        }
        float4 xjv = reinterpret_cast<const float4*>(xj)[c4];
        float xjq[4] = {xjv.x, xjv.y, xjv.z, xjv.w};
        float4 w0v, w1v, w2v;
        float* w0p = &w0v.x; float* w1p = &w1v.x; float* w2p = &w2v.x;
        #pragma unroll
        for (int q = 0; q < 4; ++q) {
            w0p[q] = a0[q] * r0[q] * xjq[q];
            w1p[q] = a1[q] * r1[q] * xjq[q];
            w2p[q] = a2[q] * r2[q] * xjq[q];
        }
        uw[c4]      = w0v;
        uw[32 + c4] = w1v;
        uw[64 + c4] = w2v;
    }

    // ---- permute SH coeffs into sorted order
    #pragma unroll
    for (int i = 0; i < 9; ++i) g_y[row * 9 + i] = edge_rsh[(size_t)e * 9 + i];
}

// One block per node, lane = channel. Registers-only accumulation, no atomics.
__global__ __launch_bounds__(128) void gather_kernel()
{
    int n = blockIdx.x;
    int c = threadIdx.x;
    int beg = g_offs[n], end = g_offs[n + 1];

    float acc[9];
    #pragma unroll
    for (int m = 0; m < 9; ++m) acc[m] = 0.f;

    for (int r = beg; r < end; ++r) {
        const float* up = g_u + (size_t)r * WND;
        float u0 = up[c], u1 = up[CC + c], u2 = up[2 * CC + c];
        const float* yp = g_y + (size_t)r * 9;
        acc[0] = fmaf(u0, yp[0], acc[0]);
        acc[1] = fmaf(u1, yp[1], acc[1]);
        acc[2] = fmaf(u1, yp[2], acc[2]);
        acc[3] = fmaf(u1, yp[3], acc[3]);
        acc[4] = fmaf(u2, yp[4], acc[4]);
        acc[5] = fmaf(u2, yp[5], acc[5]);
        acc[6] = fmaf(u2, yp[6], acc[6]);
        acc[7] = fmaf(u2, yp[7], acc[7]);
        acc[8] = fmaf(u2, yp[8], acc[8]);
    }

    float* A = g_accu + (size_t)n * MROW;
    #pragma unroll
    for (int m = 0; m < 9; ++m) A[m * CC + c] = acc[m];
}

// Node-wise linear, 2 nodes per block.
__global__ __launch_bounds__(256) void lin2_kernel(
    const float* __restrict__ W0, const float* __restrict__ b0,
    const float* __restrict__ W1, const float* __restrict__ W2,
    float* __restrict__ out)
{
    __shared__ float sA[2 * MROW];
    int n0 = blockIdx.x * 2;
    const float4* g = reinterpret_cast<const float4*>(g_accu + (size_t)n0 * MROW);
    for (int i = threadIdx.x; i < 2 * MROW / 4; i += 256)
        reinterpret_cast<float4*>(sA)[i] = g[i];
    __syncthreads();

    int d  = threadIdx.x & (CC - 1);
    int nl = threadIdx.x >> 7;
    const float* a = sA + nl * MROW;

    float acc[9];
    #pragma unroll
    for (int m = 0; m < 9; ++m) acc[m] = 0.f;

    #pragma unroll 2
    for (int c = 0; c < CC; ++c) {
        float w0 = W0[c * CC + d];
        float w1 = W1[c * CC + d];
        float w2 = W2[c * CC + d];
        acc[0] = fmaf(a[c],           w0, acc[0]);
        acc[1] = fmaf(a[CC + c],      w1, acc[1]);
        acc[2] = fmaf(a[2 * CC + c],  w1, acc[2]);
        acc[3] = fmaf(a[3 * CC + c],  w1, acc[3]);
        acc[4] = fmaf(a[4 * CC + c],  w2, acc[4]);
        acc[5] = fmaf(a[5 * CC + c],  w2, acc[5]);
        acc[6] = fmaf(a[6 * CC + c],  w2, acc[6]);
        acc[7] = fmaf(a[7 * CC + c],  w2, acc[7]);
        acc[8] = fmaf(a[8 * CC + c],  w2, acc[8]);
    }

    const float inv = 0.08838834764831845f;  // 1/sqrt(128)
    size_t ob = (size_t)(n0 + nl) * MROW;
    out[ob + d] = acc[0] * inv + b0[d];
    #pragma unroll
    for (int m = 0; m < 3; ++m) out[ob + CC + d * 3 + m]     = acc[1 + m] * inv;
    #pragma unroll
    for (int m = 0; m < 5; ++m) out[ob + 4 * CC + d * 5 + m] = acc[4 + m] * inv;
}

extern "C" void kernel_launch(void* const* d_in, const int* in_sizes, int n_in,
                              void* d_out, int out_size, void* d_ws, size_t ws_size,
                              hipStream_t stream)
{
    const float* node_feat  = (const float*)d_in[0];
    const float* edge_attr  = (const float*)d_in[1];
    const float* edge_rsh   = (const float*)d_in[2];
    const int*   edge_index = (const int*)  d_in[3];
    const float* Ws1 = (const float*)d_in[4];
    const float* bs1 = (const float*)d_in[5];
    const float* Ws2 = (const float*)d_in[6];
    const float* bs2 = (const float*)d_in[7];
    const float* Wr1 = (const float*)d_in[8];
    const float* br1 = (const float*)d_in[9];
    const float* Wr2 = (const float*)d_in[10];
    const float* br2 = (const float*)d_in[11];
    const float* W0  = (const float*)d_in[12];
    const float* b0  = (const float*)d_in[13];
    const float* W1  = (const float*)d_in[14];
    const float* W2  = (const float*)d_in[15];
    float* out = (float*)d_out;

    zero_deg_kernel<<<(NN + 255) / 256, 256, 0, stream>>>();
    hist_kernel<<<EE / 256, 256, 0, stream>>>(edge_index);
    scan_kernel<<<1, 1024, 0, stream>>>();
    mlp_kernel<<<EE / 256, 256, 0, stream>>>(
        node_feat, edge_attr, edge_rsh, edge_index,
        Ws1, bs1, Ws2, bs2, Wr1, br1, Wr2, br2);
    gather_kernel<<<NN, 128, 0, stream>>>();
    lin2_kernel<<<NN / 2, 256, 0, stream>>>(W0, b0, W1, W2, out);
}

// Round 3
// 478.613 us; speedup vs baseline: 19.9459x; 1.8966x over previous
//
#include <hip/hip_runtime.h>
#include <hip/hip_bf16.h>
#include <math.h>

#define NN   10000
#define EE   160000
#define CC   128
#define RBFD 20
#define HIDD 32
#define WND  384
#define MROW 1152   // 9*128 accumulator row: [m=0..8][c=0..127]

// Static device buffers (persist across calls; fully rewritten each call).
__device__ __align__(16) float g_h[(size_t)EE * 64];      // 41 MB: sorted hidden [row][hs(32)|hr(32)]
__device__ __align__(16) float g_y[(size_t)EE * 9];       // 5.8 MB: sorted SH coeffs
__device__ int   g_dst[EE];                               // sorted dst node per row
__device__ __align__(16) float g_accu[(size_t)NN * MROW]; // 46 MB: per-node accumulator [n][m(9)][c]
__device__ int g_deg[NN];
__device__ int g_offs[NN + 1];
__device__ int g_rel[EE];

__device__ __forceinline__ float silu_f(float x) { return x / (1.f + __expf(-x)); }

__global__ __launch_bounds__(256) void zero_deg_kernel()
{
    int i = blockIdx.x * 256 + threadIdx.x;
    if (i < NN) g_deg[i] = 0;
}

__global__ __launch_bounds__(256) void hist_kernel(const int* __restrict__ edge_index)
{
    int e = blockIdx.x * 256 + threadIdx.x;
    if (e < EE) g_rel[e] = atomicAdd(&g_deg[edge_index[e]], 1);
}

// Single-block exclusive scan over g_deg -> g_offs
__global__ __launch_bounds__(1024) void scan_kernel()
{
    __shared__ int s[1024];
    __shared__ int carry;
    if (threadIdx.x == 0) { carry = 0; g_offs[0] = 0; }
    __syncthreads();
    for (int base = 0; base < NN; base += 1024) {
        int i = base + threadIdx.x;
        int v = (i < NN) ? g_deg[i] : 0;
        s[threadIdx.x] = v;
        __syncthreads();
        for (int off = 1; off < 1024; off <<= 1) {
            int t = (threadIdx.x >= off) ? s[threadIdx.x - off] : 0;
            __syncthreads();
            s[threadIdx.x] += t;
            __syncthreads();
        }
        if (i < NN) g_offs[i + 1] = carry + s[threadIdx.x];
        __syncthreads();
        if (threadIdx.x == 0) carry += s[1023];
        __syncthreads();
    }
}

// Per-edge MLP1 (both branches). Writes hidden row (64 floats) to sorted
// position via per-wave LDS transpose -> fully coalesced 256B row stores.
__global__ __launch_bounds__(128) void mlp1_kernel(
    const float* __restrict__ node_feat,
    const float* __restrict__ edge_attr,
    const float* __restrict__ edge_rsh,
    const int*   __restrict__ edge_index,
    const float* __restrict__ Ws1, const float* __restrict__ bs1,
    const float* __restrict__ Wr1, const float* __restrict__ br1)
{
    __shared__ float sH[2][64][65];
    __shared__ int   sRow[2][64];

    int e = blockIdx.x * 128 + threadIdx.x;   // grid is exact: EE/128 blocks
    int w = threadIdx.x >> 6, l = threadIdx.x & 63;

    int s = edge_index[e];        // src (segment key)
    int t = edge_index[EE + e];   // dst (xj)
    const float* xi = node_feat + (size_t)s * CC;
    const float* xj = node_feat + (size_t)t * CC;

    // ---- MLP-s hidden
    float hs[HIDD];
    #pragma unroll
    for (int j = 0; j < HIDD; ++j) hs[j] = bs1[j];
    #pragma unroll 1
    for (int k4 = 0; k4 < CC / 4; ++k4) {
        float4 a = reinterpret_cast<const float4*>(xi)[k4];
        const float* wp = Ws1 + (4 * k4) * HIDD;
        #pragma unroll
        for (int j = 0; j < HIDD; ++j) {
            hs[j] = fmaf(a.x, wp[j],            hs[j]);
            hs[j] = fmaf(a.y, wp[HIDD + j],     hs[j]);
            hs[j] = fmaf(a.z, wp[2 * HIDD + j], hs[j]);
            hs[j] = fmaf(a.w, wp[3 * HIDD + j], hs[j]);
        }
    }
    #pragma unroll 1
    for (int k4 = 0; k4 < CC / 4; ++k4) {
        float4 a = reinterpret_cast<const float4*>(xj)[k4];
        const float* wp = Ws1 + (CC + 4 * k4) * HIDD;
        #pragma unroll
        for (int j = 0; j < HIDD; ++j) {
            hs[j] = fmaf(a.x, wp[j],            hs[j]);
            hs[j] = fmaf(a.y, wp[HIDD + j],     hs[j]);
            hs[j] = fmaf(a.z, wp[2 * HIDD + j], hs[j]);
            hs[j] = fmaf(a.w, wp[3 * HIDD + j], hs[j]);
        }
    }

    // ---- MLP-r hidden
    float hr[HIDD];
    #pragma unroll
    for (int j = 0; j < HIDD; ++j) hr[j] = br1[j];
    #pragma unroll 1
    for (int k4 = 0; k4 < RBFD / 4; ++k4) {
        float4 a = reinterpret_cast<const float4*>(edge_attr + (size_t)e * RBFD)[k4];
        const float* wp = Wr1 + (4 * k4) * HIDD;
        #pragma unroll
        for (int j = 0; j < HIDD; ++j) {
            hr[j] = fmaf(a.x, wp[j],            hr[j]);
            hr[j] = fmaf(a.y, wp[HIDD + j],     hr[j]);
            hr[j] = fmaf(a.z, wp[2 * HIDD + j], hr[j]);
            hr[j] = fmaf(a.w, wp[3 * HIDD + j], hr[j]);
        }
    }

    // ---- sorted destination row; small scattered metadata writes
    int row = g_offs[s] + g_rel[e];
    g_dst[row] = t;
    #pragma unroll
    for (int i = 0; i < 9; ++i) g_y[(size_t)row * 9 + i] = edge_rsh[(size_t)e * 9 + i];

    // ---- transpose via LDS, coalesced 256B row stores
    sRow[w][l] = row;
    #pragma unroll
    for (int j = 0; j < HIDD; ++j) {
        sH[w][l][j]        = silu_f(hs[j]);
        sH[w][l][HIDD + j] = silu_f(hr[j]);
    }
    __syncthreads();
    #pragma unroll 4
    for (int r = 0; r < 64; ++r) {
        size_t rw = (size_t)sRow[w][r];
        g_h[rw * 64 + l] = sH[w][r][l];
    }
}

// Block (128 thr) per node (grid-stride). Lane = channel. Ws2/Wr2 columns
// register-cached; hidden rows broadcast via double-buffered LDS; MLP2
// recomputed here; accumulates in registers; no atomics.
__global__ __launch_bounds__(128, 2) void gather2_kernel(
    const float* __restrict__ node_feat,
    const float* __restrict__ Ws2, const float* __restrict__ bs2,
    const float* __restrict__ Wr2, const float* __restrict__ br2)
{
    __shared__ float hbuf[2][64];
    __shared__ float ybuf[2][12];

    int c = threadIdx.x;  // 0..127

    // register-cache the 6 weight columns this lane needs
    float wS0[HIDD], wS1[HIDD], wS2c[HIDD], wR0[HIDD], wR1[HIDD], wR2c[HIDD];
    #pragma unroll
    for (int j = 0; j < HIDD; ++j) {
        wS0[j]  = Ws2[j * WND + c];
        wS1[j]  = Ws2[j * WND + CC + c];
        wS2c[j] = Ws2[j * WND + 2 * CC + c];
        wR0[j]  = Wr2[j * WND + c];
        wR1[j]  = Wr2[j * WND + CC + c];
        wR2c[j] = Wr2[j * WND + 2 * CC + c];
    }
    float b0s = bs2[c], b1s = bs2[CC + c], b2s = bs2[2 * CC + c];
    float b0r = br2[c], b1r = br2[CC + c], b2r = br2[2 * CC + c];

    for (int n = blockIdx.x; n < NN; n += gridDim.x) {
        int beg = g_offs[n], end = g_offs[n + 1];

        float acc[9];
        #pragma unroll
        for (int m = 0; m < 9; ++m) acc[m] = 0.f;

        float hpre = 0.f, ypre = 0.f, xjpre = 0.f;
        if (beg < end) {
            if (c < 64)            hpre = g_h[(size_t)beg * 64 + c];
            if (c >= 64 && c < 73) ypre = g_y[(size_t)beg * 9 + (c - 64)];
            int t0 = g_dst[beg];
            xjpre = node_feat[(size_t)t0 * CC + c];
        }

        int cur = 0;
        for (int r = beg; r < end; ++r) {
            if (c < 64)            hbuf[cur][c]      = hpre;
            if (c >= 64 && c < 73) ybuf[cur][c - 64] = ypre;
            __syncthreads();

            float xjc = xjpre;
            if (r + 1 < end) {
                if (c < 64)            hpre = g_h[(size_t)(r + 1) * 64 + c];
                if (c >= 64 && c < 73) ypre = g_y[(size_t)(r + 1) * 9 + (c - 64)];
                int tn = g_dst[r + 1];
                xjpre = node_feat[(size_t)tn * CC + c];
            }

            const float4* hb4 = reinterpret_cast<const float4*>(&hbuf[cur][0]);
            float as0 = b0s, as1 = b1s, as2 = b2s;
            float ar0 = b0r, ar1 = b1r, ar2 = b2r;
            #pragma unroll
            for (int q = 0; q < 8; ++q) {
                float4 h4 = hb4[q];
                int j = 4 * q;
                as0 = fmaf(h4.x, wS0[j],      as0); as1 = fmaf(h4.x, wS1[j],      as1); as2 = fmaf(h4.x, wS2c[j],      as2);
                as0 = fmaf(h4.y, wS0[j + 1],  as0); as1 = fmaf(h4.y, wS1[j + 1],  as1); as2 = fmaf(h4.y, wS2c[j + 1],  as2);
                as0 = fmaf(h4.z, wS0[j + 2],  as0); as1 = fmaf(h4.z, wS1[j + 2],  as1); as2 = fmaf(h4.z, wS2c[j + 2],  as2);
                as0 = fmaf(h4.w, wS0[j + 3],  as0); as1 = fmaf(h4.w, wS1[j + 3],  as1); as2 = fmaf(h4.w, wS2c[j + 3],  as2);
            }
            #pragma unroll
            for (int q = 0; q < 8; ++q) {
                float4 h4 = hb4[8 + q];
                int j = 4 * q;
                ar0 = fmaf(h4.x, wR0[j],      ar0); ar1 = fmaf(h4.x, wR1[j],      ar1); ar2 = fmaf(h4.x, wR2c[j],      ar2);
                ar0 = fmaf(h4.y, wR0[j + 1],  ar0); ar1 = fmaf(h4.y, wR1[j + 1],  ar1); ar2 = fmaf(h4.y, wR2c[j + 1],  ar2);
                ar0 = fmaf(h4.z, wR0[j + 2],  ar0); ar1 = fmaf(h4.z, wR1[j + 2],  ar1); ar2 = fmaf(h4.z, wR2c[j + 2],  ar2);
                ar0 = fmaf(h4.w, wR0[j + 3],  ar0); ar1 = fmaf(h4.w, wR1[j + 3],  ar1); ar2 = fmaf(h4.w, wR2c[j + 3],  ar2);
            }

            float w0 = as0 * ar0 * xjc;
            float w1 = as1 * ar1 * xjc;
            float w2 = as2 * ar2 * xjc;
            const float* yb = ybuf[cur];
            acc[0] = fmaf(w0, yb[0], acc[0]);
            acc[1] = fmaf(w1, yb[1], acc[1]);
            acc[2] = fmaf(w1, yb[2], acc[2]);
            acc[3] = fmaf(w1, yb[3], acc[3]);
            acc[4] = fmaf(w2, yb[4], acc[4]);
            acc[5] = fmaf(w2, yb[5], acc[5]);
            acc[6] = fmaf(w2, yb[6], acc[6]);
            acc[7] = fmaf(w2, yb[7], acc[7]);
            acc[8] = fmaf(w2, yb[8], acc[8]);

            cur ^= 1;
        }

        float* A = g_accu + (size_t)n * MROW;
        #pragma unroll
        for (int m = 0; m < 9; ++m) A[m * CC + c] = acc[m];
    }
}

// Node-wise linear, 2 nodes per block.
__global__ __launch_bounds__(256) void lin2_kernel(
    const float* __restrict__ W0, const float* __restrict__ b0,
    const float* __restrict__ W1, const float* __restrict__ W2,
    float* __restrict__ out)
{
    __shared__ float sA[2 * MROW];
    int n0 = blockIdx.x * 2;
    const float4* g = reinterpret_cast<const float4*>(g_accu + (size_t)n0 * MROW);
    for (int i = threadIdx.x; i < 2 * MROW / 4; i += 256)
        reinterpret_cast<float4*>(sA)[i] = g[i];
    __syncthreads();

    int d  = threadIdx.x & (CC - 1);
    int nl = threadIdx.x >> 7;
    const float* a = sA + nl * MROW;

    float acc[9];
    #pragma unroll
    for (int m = 0; m < 9; ++m) acc[m] = 0.f;

    #pragma unroll 2
    for (int cc = 0; cc < CC; ++cc) {
        float w0 = W0[cc * CC + d];
        float w1 = W1[cc * CC + d];
        float w2 = W2[cc * CC + d];
        acc[0] = fmaf(a[cc],           w0, acc[0]);
        acc[1] = fmaf(a[CC + cc],      w1, acc[1]);
        acc[2] = fmaf(a[2 * CC + cc],  w1, acc[2]);
        acc[3] = fmaf(a[3 * CC + cc],  w1, acc[3]);
        acc[4] = fmaf(a[4 * CC + cc],  w2, acc[4]);
        acc[5] = fmaf(a[5 * CC + cc],  w2, acc[5]);
        acc[6] = fmaf(a[6 * CC + cc],  w2, acc[6]);
        acc[7] = fmaf(a[7 * CC + cc],  w2, acc[7]);
        acc[8] = fmaf(a[8 * CC + cc],  w2, acc[8]);
    }

    const float inv = 0.08838834764831845f;  // 1/sqrt(128)
    size_t ob = (size_t)(n0 + nl) * MROW;
    out[ob + d] = acc[0] * inv + b0[d];
    #pragma unroll
    for (int m = 0; m < 3; ++m) out[ob + CC + d * 3 + m]     = acc[1 + m] * inv;
    #pragma unroll
    for (int m = 0; m < 5; ++m) out[ob + 4 * CC + d * 5 + m] = acc[4 + m] * inv;
}

extern "C" void kernel_launch(void* const* d_in, const int* in_sizes, int n_in,
                              void* d_out, int out_size, void* d_ws, size_t ws_size,
                              hipStream_t stream)
{
    const float* node_feat  = (const float*)d_in[0];
    const float* edge_attr  = (const float*)d_in[1];
    const float* edge_rsh   = (const float*)d_in[2];
    const int*   edge_index = (const int*)  d_in[3];
    const float* Ws1 = (const float*)d_in[4];
    const float* bs1 = (const float*)d_in[5];
    const float* Ws2 = (const float*)d_in[6];
    const float* bs2 = (const float*)d_in[7];
    const float* Wr1 = (const float*)d_in[8];
    const float* br1 = (const float*)d_in[9];
    const float* Wr2 = (const float*)d_in[10];
    const float* br2 = (const float*)d_in[11];
    const float* W0  = (const float*)d_in[12];
    const float* b0  = (const float*)d_in[13];
    const float* W1  = (const float*)d_in[14];
    const float* W2  = (const float*)d_in[15];
    float* out = (float*)d_out;

    zero_deg_kernel<<<(NN + 255) / 256, 256, 0, stream>>>();
    hist_kernel<<<EE / 256, 256, 0, stream>>>(edge_index);
    scan_kernel<<<1, 1024, 0, stream>>>();
    mlp1_kernel<<<EE / 128, 128, 0, stream>>>(
        node_feat, edge_attr, edge_rsh, edge_index, Ws1, bs1, Wr1, br1);
    gather2_kernel<<<1024, 128, 0, stream>>>(node_feat, Ws2, bs2, Wr2, br2);
    lin2_kernel<<<NN / 2, 256, 0, stream>>>(W0, b0, W1, W2, out);
}